// Round 1
// baseline (203.676 us; speedup 1.0000x reference)
//
#include <hip/hip_runtime.h>
#include <stdint.h>

typedef unsigned long long u64;
typedef unsigned int u32;

#define NSHIFT 15      // max |shift|
#define NACC   31      // shifts -15..15
#define NPAIRS 8192    // 2 * 4096 rows
#define CODE_L 2048    // code length (roll axis)
#define GROUPS 32      // 2048 bits / 64 lanes

// Each wave processes whole (c,b) rows. Row layout in memory: for fixed
// (c,b), 2048 ushorts, ushort l = byte(p=0) | byte(p=1)<<8.
// Packed representation: per p, a 2048-bit ring = 32 u64 words.
// Lane w (w<32) holds p0 word w; lane 32+w holds p1 word w.
__global__ __launch_bounds__(256) void hd_main(
    const unsigned char* __restrict__ ia8,
    const unsigned char* __restrict__ ma8,
    const unsigned char* __restrict__ ib8,
    const unsigned char* __restrict__ mb8,
    u32* __restrict__ partials, int nblocks)
{
    const int tid  = threadIdx.x;
    const int lane = tid & 63;
    const int wv   = tid >> 6;                 // wave in block (0..3)
    const int gw   = blockIdx.x * 4 + wv;      // global wave id
    const int nw   = nblocks * 4;

    const unsigned short* ia = (const unsigned short*)ia8;
    const unsigned short* ma = (const unsigned short*)ma8;
    const unsigned short* ib = (const unsigned short*)ib8;
    const unsigned short* mb = (const unsigned short*)mb8;

    u32 num[NACC], den[NACC];
#pragma unroll
    for (int j = 0; j < NACC; ++j) { num[j] = 0u; den[j] = 0u; }

    // ring neighbors within the same p-half (32-word ring)
    const int prevLane = (lane & 32) | ((lane + 31) & 31);
    const int nextLane = (lane & 32) | ((lane + 1) & 31);

    for (int r = gw; r < NPAIRS; r += nw) {
        const unsigned short* ra_ = ia + (size_t)r * CODE_L;
        const unsigned short* rm_ = ma + (size_t)r * CODE_L;
        const unsigned short* rb_ = ib + (size_t)r * CODE_L;
        const unsigned short* rn_ = mb + (size_t)r * CODE_L;

        u64 wia = 0, wma = 0, wib = 0, wmb = 0;
#pragma unroll
        for (int g = 0; g < GROUPS; ++g) {
            const int l = g * 64 + lane;
            const unsigned int va = ra_[l];
            const unsigned int vm = rm_[l];
            const unsigned int vb = rb_[l];
            const unsigned int vn = rn_[l];
            // bit i of ballot = lane i's predicate = l = 64g+i  (in-order packing)
            u64 a0 = __ballot(va & 1u);
            u64 a1 = __ballot(va & 256u);
            u64 m0 = __ballot(vm & 1u);
            u64 m1 = __ballot(vm & 256u);
            u64 b0 = __ballot(vb & 1u);
            u64 b1 = __ballot(vb & 256u);
            u64 n0 = __ballot(vn & 1u);
            u64 n1 = __ballot(vn & 256u);
            if (lane == g)      { wia = a0; wma = m0; wib = b0; wmb = n0; }
            if (lane == g + 32) { wia = a1; wma = m1; wib = b1; wmb = n1; }
        }

        // neighbor words for cross-word bit spill (|s| <= 15 < 64)
        const u64 pia = __shfl(wia, prevLane, 64);
        const u64 nia = __shfl(wia, nextLane, 64);
        const u64 pma = __shfl(wma, prevLane, 64);
        const u64 nma = __shfl(wma, nextLane, 64);

        {   // shift 0
            const u64 mk = wma & wmb;
            num[15] += (u32)__popcll((wia ^ wib) & mk);
            den[15] += (u32)__popcll(mk);
        }
#pragma unroll
        for (int s = 1; s <= NSHIFT; ++s) {
            {   // roll right by s: rolled[l] = orig[l-s]
                const u64 rra = (wia << s) | (pia >> (64 - s));
                const u64 rrm = (wma << s) | (pma >> (64 - s));
                const u64 mk  = rrm & wmb;
                num[15 + s] += (u32)__popcll((rra ^ wib) & mk);
                den[15 + s] += (u32)__popcll(mk);
            }
            {   // roll left by s: rolled[l] = orig[l+s]
                const u64 rra = (wia >> s) | (nia << (64 - s));
                const u64 rrm = (wma >> s) | (nma << (64 - s));
                const u64 mk  = rrm & wmb;
                num[15 - s] += (u32)__popcll((rra ^ wib) & mk);
                den[15 - s] += (u32)__popcll(mk);
            }
        }
    }

    // wave-reduce each accumulator, combine 4 waves in LDS, write block partials
    __shared__ u32 lds[4][2 * NACC];
#pragma unroll
    for (int j = 0; j < NACC; ++j) {
        u32 n = num[j], d = den[j];
#pragma unroll
        for (int o = 32; o > 0; o >>= 1) {
            n += __shfl_xor(n, o, 64);
            d += __shfl_xor(d, o, 64);
        }
        if (lane == 0) { lds[wv][2 * j] = n; lds[wv][2 * j + 1] = d; }
    }
    __syncthreads();
    if (tid < 2 * NACC) {
        partials[(size_t)blockIdx.x * (2 * NACC) + tid] =
            lds[0][tid] + lds[1][tid] + lds[2][tid] + lds[3][tid];
    }
}

// One wave: sum the per-block partials, do the 31 divisions, min, clamp to 1.
__global__ void hd_finalize(const u32* __restrict__ partials, int nblocks,
                            float* __restrict__ out)
{
    const int lane = threadIdx.x;   // 64 threads
    float best = 1.0f;
#pragma unroll
    for (int j = 0; j < NACC; ++j) {
        u32 n = 0u, d = 0u;
        for (int b = lane; b < nblocks; b += 64) {
            n += partials[(size_t)b * (2 * NACC) + 2 * j];
            d += partials[(size_t)b * (2 * NACC) + 2 * j + 1];
        }
#pragma unroll
        for (int o = 32; o > 0; o >>= 1) {
            n += __shfl_xor(n, o, 64);
            d += __shfl_xor(d, o, 64);
        }
        const float f = (float)n / (float)d;
        best = fminf(best, f);
    }
    if (lane == 0) out[0] = best;
}

extern "C" void kernel_launch(void* const* d_in, const int* in_sizes, int n_in,
                              void* d_out, int out_size, void* d_ws, size_t ws_size,
                              hipStream_t stream)
{
    const unsigned char* ia = (const unsigned char*)d_in[0];  // iris_codes_a
    const unsigned char* ma = (const unsigned char*)d_in[1];  // mask_codes_a
    const unsigned char* ib = (const unsigned char*)d_in[2];  // iris_codes_b
    const unsigned char* mb = (const unsigned char*)d_in[3];  // mask_codes_b
    float* out = (float*)d_out;
    u32* partials = (u32*)d_ws;

    int nblocks = 2048;  // 256 thr = 4 waves/block -> 8192 waves, 1 row each
    while (nblocks > 1 && (size_t)nblocks * (2 * NACC) * sizeof(u32) > ws_size)
        nblocks >>= 1;

    hd_main<<<dim3(nblocks), dim3(256), 0, stream>>>(ia, ma, ib, mb, partials, nblocks);
    hd_finalize<<<dim3(1), dim3(64), 0, stream>>>(partials, nblocks, out);
}

// Round 2
// 66.460 us; speedup vs baseline: 3.0646x; 3.0646x over previous
//
#include <hip/hip_runtime.h>
#include <stdint.h>

typedef unsigned long long u64;
typedef unsigned int u32;
typedef unsigned short u16;

#define NSHIFT 15      // max |shift|
#define NACC   31      // shifts -15..15
#define NPAIRS 8192    // 2 * 4096 rows
#define CODE_L 2048    // code length (roll axis)
#define NBLK   1024    // 1024 blocks * 4 waves = 4096 waves, 2 rows each

// Wave-per-2-rows. Row layout: 2048 ushorts, ushort l = p0 byte | p1 byte<<8.
// Packed: per plane a 2048-bit ring = 32 u64 words; lane w (w<32) holds p0
// word w; lane 32+w holds p1 word w. Packing via __ballot (1 v_cmp fills a
// 64-bit word across lanes).
__global__ __launch_bounds__(256) void hd_main(
    const u16* __restrict__ ia, const u16* __restrict__ ma,
    const u16* __restrict__ ib, const u16* __restrict__ mb,
    u32* __restrict__ counters)
{
    const int tid  = threadIdx.x;
    const int lane = tid & 63;
    const int wv   = tid >> 6;
    const int gw   = blockIdx.x * 4 + wv;          // 0..4095, one row-pair each

    u32 num[NACC], den[NACC];
#pragma unroll
    for (int j = 0; j < NACC; ++j) { num[j] = 0u; den[j] = 0u; }

    // ring neighbors within the same plane-half (32-word ring)
    const int prevLane = (lane & 32) | ((lane + 31) & 31);
    const int nextLane = (lane & 32) | ((lane + 1) & 31);

    const size_t base = (size_t)gw * 2 * CODE_L;   // row A; row B = base+CODE_L

    u64 wiaA = 0, wmaA = 0, wibA = 0, wmbA = 0;
    u64 wiaB = 0, wmaB = 0, wibB = 0, wmbB = 0;

#pragma unroll
    for (int g = 0; g < 32; ++g) {
        const int l = g * 64 + lane;
        const u32 vaA = ia[base + l];
        const u32 vmA = ma[base + l];
        const u32 vbA = ib[base + l];
        const u32 vnA = mb[base + l];
        const u32 vaB = ia[base + CODE_L + l];
        const u32 vmB = ma[base + CODE_L + l];
        const u32 vbB = ib[base + CODE_L + l];
        const u32 vnB = mb[base + CODE_L + l];

        const u64 a0A = __ballot(vaA & 1u);
        const u64 a1A = __ballot(vaA & 256u);
        const u64 m0A = __ballot(vmA & 1u);
        const u64 m1A = __ballot(vmA & 256u);
        const u64 b0A = __ballot(vbA & 1u);
        const u64 b1A = __ballot(vbA & 256u);
        const u64 n0A = __ballot(vnA & 1u);
        const u64 n1A = __ballot(vnA & 256u);
        const u64 a0B = __ballot(vaB & 1u);
        const u64 a1B = __ballot(vaB & 256u);
        const u64 m0B = __ballot(vmB & 1u);
        const u64 m1B = __ballot(vmB & 256u);
        const u64 b0B = __ballot(vbB & 1u);
        const u64 b1B = __ballot(vbB & 256u);
        const u64 n0B = __ballot(vnB & 1u);
        const u64 n1B = __ballot(vnB & 256u);

        if (lane == g) {
            wiaA = a0A; wmaA = m0A; wibA = b0A; wmbA = n0A;
            wiaB = a0B; wmaB = m0B; wibB = b0B; wmbB = n0B;
        }
        if (lane == g + 32) {
            wiaA = a1A; wmaA = m1A; wibA = b1A; wmbA = n1A;
            wiaB = a1B; wmaB = m1B; wibB = b1B; wmbB = n1B;
        }
    }

#define DO_ROW(wia, wma, wib, wmb) do {                                   \
        const u64 pia = __shfl((wia), prevLane, 64);                      \
        const u64 nia = __shfl((wia), nextLane, 64);                      \
        const u64 pma = __shfl((wma), prevLane, 64);                      \
        const u64 nma = __shfl((wma), nextLane, 64);                      \
        { const u64 mk = (wma) & (wmb);                                   \
          num[15] += (u32)__popcll(((wia) ^ (wib)) & mk);                 \
          den[15] += (u32)__popcll(mk); }                                 \
        _Pragma("unroll")                                                 \
        for (int s = 1; s <= NSHIFT; ++s) {                               \
            { /* roll right by s: rolled[l] = orig[l-s] */                \
              const u64 rra = ((wia) << s) | (pia >> (64 - s));           \
              const u64 rrm = ((wma) << s) | (pma >> (64 - s));           \
              const u64 mk  = rrm & (wmb);                                \
              num[15 + s] += (u32)__popcll((rra ^ (wib)) & mk);           \
              den[15 + s] += (u32)__popcll(mk); }                         \
            { /* roll left by s */                                        \
              const u64 rra = ((wia) >> s) | (nia << (64 - s));           \
              const u64 rrm = ((wma) >> s) | (nma << (64 - s));           \
              const u64 mk  = rrm & (wmb);                                \
              num[15 - s] += (u32)__popcll((rra ^ (wib)) & mk);           \
              den[15 - s] += (u32)__popcll(mk); }                         \
        }                                                                 \
    } while (0)

    DO_ROW(wiaA, wmaA, wibA, wmbA);
    DO_ROW(wiaB, wmaB, wibB, wmbB);
#undef DO_ROW

    // packed reduction: num | den<<16  (per-lane <=128 each, wave sum <=8192)
    __shared__ u32 lds[4][NACC];
#pragma unroll
    for (int j = 0; j < NACC; ++j) {
        u32 r = num[j] | (den[j] << 16);
#pragma unroll
        for (int o = 32; o > 0; o >>= 1) r += __shfl_xor(r, o, 64);
        if (lane == 0) lds[wv][j] = r;
    }
    __syncthreads();
    if (tid < NACC) {
        const u32 s = (lds[0][tid] & 0xFFFFu) + (lds[1][tid] & 0xFFFFu)
                    + (lds[2][tid] & 0xFFFFu) + (lds[3][tid] & 0xFFFFu);
        atomicAdd(&counters[tid], s);
    } else if (tid >= 64 && tid < 64 + NACC) {
        const int j = tid - 64;
        const u32 s = (lds[0][j] >> 16) + (lds[1][j] >> 16)
                    + (lds[2][j] >> 16) + (lds[3][j] >> 16);
        atomicAdd(&counters[NACC + j], s);
    }
}

// One wave: 31 divisions, min, clamp to 1.
__global__ void hd_finalize(const u32* __restrict__ counters,
                            float* __restrict__ out)
{
    const int lane = threadIdx.x;   // 64 threads
    float f = 1.0f;
    if (lane < NACC) {
        f = (float)counters[lane] / (float)counters[NACC + lane];
    }
#pragma unroll
    for (int o = 32; o > 0; o >>= 1) f = fminf(f, __shfl_xor(f, o, 64));
    if (lane == 0) out[0] = fminf(f, 1.0f);
}

extern "C" void kernel_launch(void* const* d_in, const int* in_sizes, int n_in,
                              void* d_out, int out_size, void* d_ws, size_t ws_size,
                              hipStream_t stream)
{
    const u16* ia = (const u16*)d_in[0];  // iris_codes_a
    const u16* ma = (const u16*)d_in[1];  // mask_codes_a
    const u16* ib = (const u16*)d_in[2];  // iris_codes_b
    const u16* mb = (const u16*)d_in[3];  // mask_codes_b
    u32* counters = (u32*)d_ws;           // 62 u32

    hipMemsetAsync(d_ws, 0, 2 * NACC * sizeof(u32), stream);
    hd_main<<<dim3(NBLK), dim3(256), 0, stream>>>(ia, ma, ib, mb, counters);
    hd_finalize<<<dim3(1), dim3(64), 0, stream>>>(counters, (float*)d_out);
}

// Round 3
// 35.756 us; speedup vs baseline: 5.6963x; 1.8587x over previous
//
#include <hip/hip_runtime.h>
#include <stdint.h>

typedef unsigned long long u64;
typedef unsigned int u32;

#define NACC    31
#define NSHIFT  15
#define NROWS   8192      // 2 * 4096 (c,b) rows
#define ROWB    4096      // bytes per row: 2048 positions * 2 planes
#define NBLK    2048      // 2048 blocks * 4 waves = 8192 waves, 1 row each
#define NSHADOW 32        // shadow copies of the 62 global counters

// De-interleave planes and pack 0/1 bytes to bits.
// v = 16 bytes at positions q..q+7 (byte 2i = plane0(q+i), 2i+1 = plane1(q+i)).
// Appends 8 bits to P0 (plane0) and P1 (plane1) at bit offset 8t.
// Multiply trick: quad bytes b0..b3 (each 0/1): (quad * 0x01020408) has
// b0,b1,b2,b3 at bits 24..27 with no carries (all partial products distinct).
__device__ __forceinline__ void pack16(uint4 v, u32& P0, u32& P1, int t) {
    const u32 q0 = __byte_perm(v.x, v.y, 0x6420);  // plane0, positions q..q+3
    const u32 q1 = __byte_perm(v.x, v.y, 0x7531);  // plane1, positions q..q+3
    const u32 q2 = __byte_perm(v.z, v.w, 0x6420);  // plane0, q+4..q+7
    const u32 q3 = __byte_perm(v.z, v.w, 0x7531);  // plane1, q+4..q+7
    const u32 n0 = (q0 * 0x01020408u) >> 24;
    const u32 n1 = (q1 * 0x01020408u) >> 24;
    const u32 n2 = (q2 * 0x01020408u) >> 24;
    const u32 n3 = (q3 * 0x01020408u) >> 24;
    P0 |= (n0 | (n2 << 4)) << (8 * t);
    P1 |= (n1 | (n3 << 4)) << (8 * t);
}

// One wave per row. Lane l owns positions 32l..32l+31 as one u32 per plane
// (bit j = position 32l+j). Ring = exactly the 64-lane wave (64*32 = 2048).
// Rotation by |s|<=15 needs only lane+-1 neighbors (8 shfls per row).
__global__ __launch_bounds__(256) void hd_main(
    const unsigned char* __restrict__ ia, const unsigned char* __restrict__ ma,
    const unsigned char* __restrict__ ib, const unsigned char* __restrict__ mb,
    u32* __restrict__ cnt)
{
    const int tid  = threadIdx.x;
    const int lane = tid & 63;
    const int row  = blockIdx.x * 4 + (tid >> 6);   // 0..8191

    u32 acc[NACC];                                  // num | den<<16 (each <=64)
#pragma unroll
    for (int j = 0; j < NACC; ++j) acc[j] = 0u;

    const int prevL = (lane + 63) & 63;
    const int nextL = (lane + 1) & 63;

    {
        const uint4* pa = (const uint4*)(ia + (size_t)row * ROWB) + lane * 4;
        const uint4* pm = (const uint4*)(ma + (size_t)row * ROWB) + lane * 4;
        const uint4* pb = (const uint4*)(ib + (size_t)row * ROWB) + lane * 4;
        const uint4* pn = (const uint4*)(mb + (size_t)row * ROWB) + lane * 4;

        u32 A0 = 0, A1 = 0, M0 = 0, M1 = 0, B0 = 0, B1 = 0, N0 = 0, N1 = 0;
#pragma unroll
        for (int t = 0; t < 4; ++t) {
            const uint4 va = pa[t];
            const uint4 vm = pm[t];
            const uint4 vb = pb[t];
            const uint4 vn = pn[t];
            pack16(va, A0, A1, t);
            pack16(vm, M0, M1, t);
            pack16(vb, B0, B1, t);
            pack16(vn, N0, N1, t);
        }

        const u32 pA0 = __shfl(A0, prevL, 64), pA1 = __shfl(A1, prevL, 64);
        const u32 pM0 = __shfl(M0, prevL, 64), pM1 = __shfl(M1, prevL, 64);
        const u32 nA0 = __shfl(A0, nextL, 64), nA1 = __shfl(A1, nextL, 64);
        const u32 nM0 = __shfl(M0, nextL, 64), nM1 = __shfl(M1, nextL, 64);

        {   // s = 0
            const u32 k0 = M0 & N0, k1 = M1 & N1;
            const u32 nm = __popc((A0 ^ B0) & k0) + __popc((A1 ^ B1) & k1);
            const u32 dn = __popc(k0) + __popc(k1);
            acc[15] += nm | (dn << 16);
        }
#pragma unroll
        for (int s = 1; s <= NSHIFT; ++s) {
            {   // roll right by s: rolled[p] = orig[p-s]
                const u32 ra0 = (A0 << s) | (pA0 >> (32 - s));
                const u32 ra1 = (A1 << s) | (pA1 >> (32 - s));
                const u32 rm0 = (M0 << s) | (pM0 >> (32 - s));
                const u32 rm1 = (M1 << s) | (pM1 >> (32 - s));
                const u32 k0 = rm0 & N0, k1 = rm1 & N1;
                const u32 nm = __popc((ra0 ^ B0) & k0) + __popc((ra1 ^ B1) & k1);
                const u32 dn = __popc(k0) + __popc(k1);
                acc[15 + s] += nm | (dn << 16);
            }
            {   // roll left by s: rolled[p] = orig[p+s]
                const u32 ra0 = (A0 >> s) | (nA0 << (32 - s));
                const u32 ra1 = (A1 >> s) | (nA1 << (32 - s));
                const u32 rm0 = (M0 >> s) | (nM0 << (32 - s));
                const u32 rm1 = (M1 >> s) | (nM1 << (32 - s));
                const u32 k0 = rm0 & N0, k1 = rm1 & N1;
                const u32 nm = __popc((ra0 ^ B0) & k0) + __popc((ra1 ^ B1) & k1);
                const u32 dn = __popc(k0) + __popc(k1);
                acc[15 - s] += nm | (dn << 16);
            }
        }
    }

    // Block-wide reduction: 31 KB LDS, one pass, no per-wave butterflies.
    __shared__ alignas(16) u32 red[NACC][264];   // 264 = 256 + 8 pad (banks)
#pragma unroll
    for (int j = 0; j < NACC; ++j) red[j][tid] = acc[j];
    __syncthreads();

    if (tid < 248) {                 // 8 threads per accumulator
        const int j = tid >> 3, c = tid & 7;
        u32 ns = 0, ds = 0;
#pragma unroll
        for (int i = 0; i < 8; ++i) {
            const uint4 v = *(const uint4*)&red[j][c * 32 + i * 4];
            ns += (v.x & 0xFFFFu) + (v.y & 0xFFFFu) + (v.z & 0xFFFFu) + (v.w & 0xFFFFu);
            ds += (v.x >> 16) + (v.y >> 16) + (v.z >> 16) + (v.w >> 16);
        }
#pragma unroll
        for (int o = 1; o < 8; o <<= 1) {
            ns += __shfl_xor(ns, o, 64);
            ds += __shfl_xor(ds, o, 64);
        }
        if (c == 0) {
            const int sh = blockIdx.x & (NSHADOW - 1);
            atomicAdd(&cnt[sh * 62 + j], ns);
            atomicAdd(&cnt[sh * 62 + 31 + j], ds);
        }
    }
}

// One block: fold the 32 shadow copies, 31 divisions, min, clamp to 1.
__global__ void hd_finalize(const u32* __restrict__ cnt, float* __restrict__ out)
{
    __shared__ float fs[64];
    const int tid = threadIdx.x;     // 64 threads
    u32 s = 0;
    if (tid < 62) {
#pragma unroll
        for (int sh = 0; sh < NSHADOW; ++sh) s += cnt[sh * 62 + tid];
    }
    fs[tid < 62 ? tid : 63] = (float)s;
    __syncthreads();
    float f = 1.0f;
    if (tid < NACC) f = fs[tid] / fs[31 + tid];
#pragma unroll
    for (int o = 32; o > 0; o >>= 1) f = fminf(f, __shfl_xor(f, o, 64));
    if (tid == 0) out[0] = fminf(f, 1.0f);
}

extern "C" void kernel_launch(void* const* d_in, const int* in_sizes, int n_in,
                              void* d_out, int out_size, void* d_ws, size_t ws_size,
                              hipStream_t stream)
{
    const unsigned char* ia = (const unsigned char*)d_in[0];  // iris_codes_a
    const unsigned char* ma = (const unsigned char*)d_in[1];  // mask_codes_a
    const unsigned char* ib = (const unsigned char*)d_in[2];  // iris_codes_b
    const unsigned char* mb = (const unsigned char*)d_in[3];  // mask_codes_b
    u32* cnt = (u32*)d_ws;                                    // [32][62]

    hipMemsetAsync(d_ws, 0, NSHADOW * 62 * sizeof(u32), stream);
    hd_main<<<dim3(NBLK), dim3(256), 0, stream>>>(ia, ma, ib, mb, cnt);
    hd_finalize<<<dim3(1), dim3(64), 0, stream>>>(cnt, (float*)d_out);
}